// Round 17
// baseline (127.378 us; speedup 1.0000x reference)
//
#include <hip/hip_runtime.h>
#include <math.h>

#define D_    256
#define N_    1024
#define B_    8
#define H_    8
#define DV_   32
#define HID_  1024
#define ROWS_ (B_*N_)   // 8192

typedef _Float16 f16;
typedef __attribute__((ext_vector_type(8))) _Float16 f16x8;
typedef __attribute__((ext_vector_type(4))) _Float16 f16x4;
typedef __attribute__((ext_vector_type(8))) short s16x8;
typedef __attribute__((ext_vector_type(4))) float f32x4;

#define LO_SCALE   2048.0f
#define INV_LO     (1.0f/2048.0f)
#define INV_LO2    (1.0f/4194304.0f)

__device__ __forceinline__ unsigned short f2bf(float f) {
    unsigned u = __float_as_uint(f);
    unsigned r = (u + 0x7fffu + ((u >> 16) & 1u)) >> 16;
    return (unsigned short)r;
}
__device__ __forceinline__ float bf2f(unsigned short u) {
    return __uint_as_float((unsigned)u << 16);
}

// fast erf (Abramowitz-Stegun 7.1.26, |err| < 1.5e-7)
__device__ __forceinline__ float erf_fast(float x) {
    float ax = fabsf(x);
    float t = 1.f / (1.f + 0.3275911f * ax);
    float y = ((((1.061405429f * t - 1.453152027f) * t + 1.421413741f) * t
                - 0.284496736f) * t + 0.254829592f) * t;
    float e = __expf(-ax * ax);
    float r = 1.f - y * e;
    return x < 0.f ? -r : r;
}
__device__ __forceinline__ float gelu(float v) {
    return 0.5f * v * (1.f + erf_fast(v * 0.70710678118f));
}

// ---------------- front: LayerNorm (bid<2048) + prep GEMM/transposes (bid>=2048)
__global__ __launch_bounds__(256) void k_front(const float* __restrict__ x,
        const float* __restrict__ g, const float* __restrict__ b,
        const float* __restrict__ w_down, const float* __restrict__ b_down,
        const float* __restrict__ w_kv, const float* __restrict__ w_outer,
        const float* __restrict__ w_inner,
        float* __restrict__ pre, unsigned short* __restrict__ pbf,
        float* __restrict__ resbuf, unsigned short* __restrict__ wvT,
        unsigned short* __restrict__ woT, unsigned short* __restrict__ wiT) {
    __shared__ float smem[64 * 65];
    int t = threadIdx.x;
    int bid0 = blockIdx.x;
    if (bid0 < 2048) {
        int lane = t & 63;
        int row = bid0 * 4 + (t >> 6);
        const float4 v = ((const float4*)(x + row * D_))[lane];
        float s  = v.x + v.y + v.z + v.w;
        float sq = v.x*v.x + v.y*v.y + v.z*v.z + v.w*v.w;
        #pragma unroll
        for (int o = 32; o; o >>= 1) { s += __shfl_xor(s, o); sq += __shfl_xor(sq, o); }
        float m   = s * (1.0f / D_);
        float var = sq * (1.0f / D_) - m * m;
        float rs  = rsqrtf(var + 1e-5f);
        const float4 gv = ((const float4*)g)[lane];
        const float4 bv = ((const float4*)b)[lane];
        float4 o;
        o.x = (v.x - m) * rs * gv.x + bv.x;
        o.y = (v.y - m) * rs * gv.y + bv.y;
        o.z = (v.z - m) * rs * gv.z + bv.z;
        o.w = (v.w - m) * rs * gv.w + bv.w;
        ((float4*)(pre + row * D_))[lane] = o;
        ushort4 u4;
        u4.x = f2bf(o.x); u4.y = f2bf(o.y); u4.z = f2bf(o.z); u4.w = f2bf(o.w);
        *(ushort4*)(pbf + (size_t)row * D_ + lane * 4) = u4;
        return;
    }
    int bid = bid0 - 2048;
    if (bid < 128) {
        float (*As)[64] = (float(*)[64])smem;
        float (*Bs)[64] = (float(*)[64])(smem + 16 * 64);
        int rowBase = bid * 64;
        int tx = t & 15, ty = t >> 4;
        int arow = t >> 2, ak = (t & 3) * 4;
        int bk = t >> 4, bn = (t & 15) * 4;
        float acc[4][4] = {};
        for (int kt = 0; kt < 256; kt += 16) {
            float4 av = *(const float4*)(x + (rowBase + arow) * 256 + kt + ak);
            As[ak+0][arow] = av.x; As[ak+1][arow] = av.y;
            As[ak+2][arow] = av.z; As[ak+3][arow] = av.w;
            float4 bv = make_float4(0.f, 0.f, 0.f, 0.f);
            if (bn < 32)
                bv = *(const float4*)(w_down + (kt + bk) * 32 + bn);
            *(float4*)&Bs[bk][bn] = bv;
            __syncthreads();
            #pragma unroll
            for (int kk = 0; kk < 16; ++kk) {
                float4 a4 = *(const float4*)&As[kk][ty*4];
                float4 b4 = *(const float4*)&Bs[kk][tx*4];
                acc[0][0] += a4.x*b4.x; acc[0][1] += a4.x*b4.y; acc[0][2] += a4.x*b4.z; acc[0][3] += a4.x*b4.w;
                acc[1][0] += a4.y*b4.x; acc[1][1] += a4.y*b4.y; acc[1][2] += a4.y*b4.z; acc[1][3] += a4.y*b4.w;
                acc[2][0] += a4.z*b4.x; acc[2][1] += a4.z*b4.y; acc[2][2] += a4.z*b4.z; acc[2][3] += a4.z*b4.w;
                acc[3][0] += a4.w*b4.x; acc[3][1] += a4.w*b4.y; acc[3][2] += a4.w*b4.z; acc[3][3] += a4.w*b4.w;
            }
            __syncthreads();
        }
        int col = tx * 4;
        if (col < 32) {
            float4 bb = *(const float4*)(b_down + col);
            #pragma unroll
            for (int i = 0; i < 4; ++i) {
                float4 o;
                o.x = acc[i][0] + bb.x; o.y = acc[i][1] + bb.y;
                o.z = acc[i][2] + bb.z; o.w = acc[i][3] + bb.w;
                *(float4*)(resbuf + (rowBase + ty*4 + i) * 32 + col) = o;
            }
        }
    } else {
        const float* src; unsigned short* dst;
        int srcCols, dstCols, r0, c0;
        if (bid < 144) {
            int s2 = bid - 128;
            src = w_kv + 256; dst = wvT; srcCols = 512; dstCols = 256;
            r0 = (s2 >> 2) * 64; c0 = (s2 & 3) * 64;
        } else if (bid < 208) {
            int s2 = bid - 144;
            src = w_outer; dst = woT; srcCols = 256; dstCols = 1024;
            r0 = (s2 >> 2) * 64; c0 = (s2 & 3) * 64;
        } else {
            int s2 = bid - 208;
            src = w_inner; dst = wiT; srcCols = 1024; dstCols = 64;
            r0 = 0; c0 = s2 * 64;
        }
        float (*t64)[65] = (float(*)[65])smem;
        #pragma unroll
        for (int e = t; e < 4096; e += 256) {
            int r = e >> 6, c = e & 63;
            t64[r][c] = src[(size_t)(r0 + r) * srcCols + c0 + c];
        }
        __syncthreads();
        #pragma unroll
        for (int e = t; e < 4096; e += 256) {
            int c = e >> 6, r = e & 63;
            dst[(size_t)(c0 + c) * dstCols + r0 + r] = f2bf(t64[r][c]);
        }
    }
}

// ---------------- merged GEMMs: bid<640 K|q fp32->hi/lo f16 ; bid>=640 V bf16 MFMA
// Both depend only on k_front outputs (pre/pbf + wvT), so they share a dispatch.
__global__ __launch_bounds__(256) void k_gemms(const float* __restrict__ A,
        const unsigned short* __restrict__ Abf, const float* __restrict__ Bm,
        const float* __restrict__ Bq, const unsigned short* __restrict__ Bt,
        f16* __restrict__ khi, f16* __restrict__ klo,
        f16* __restrict__ qhi, f16* __restrict__ qlo,
        unsigned short* __restrict__ V) {
    __shared__ __align__(16) unsigned char smem[32768];
    int t = threadIdx.x;
    int bid = blockIdx.x;
    if (bid < 640) {
        // ---- K|q fp32 GEMM (exact R16 k_gemmK)
        float (*As)[64] = (float(*)[64])smem;
        float (*Bs)[64] = (float(*)[64])(smem + 4096);
        int bx = bid % 5;
        int nBase = bx * 64, rowBase = (bid / 5) * 64;
        int tx = t & 15, ty = t >> 4;
        int arow = t >> 2, ak = (t & 3) * 4;
        int bk = t >> 4, bn = (t & 15) * 4;
        float acc[4][4] = {};
        for (int kt = 0; kt < 256; kt += 16) {
            float4 av = *(const float4*)(A + (rowBase + arow) * 256 + kt + ak);
            As[ak+0][arow] = av.x; As[ak+1][arow] = av.y;
            As[ak+2][arow] = av.z; As[ak+3][arow] = av.w;
            float4 bv = make_float4(0.f, 0.f, 0.f, 0.f);
            if (bx < 4)
                bv = *(const float4*)(Bm + (size_t)(kt + bk) * 512 + nBase + bn);
            else if (bn < 32)
                bv = *(const float4*)(Bq + (size_t)(kt + bk) * 32 + bn);
            *(float4*)&Bs[bk][bn] = bv;
            __syncthreads();
            #pragma unroll
            for (int kk = 0; kk < 16; ++kk) {
                float4 a4 = *(const float4*)&As[kk][ty*4];
                float4 b4 = *(const float4*)&Bs[kk][tx*4];
                acc[0][0] += a4.x*b4.x; acc[0][1] += a4.x*b4.y; acc[0][2] += a4.x*b4.z; acc[0][3] += a4.x*b4.w;
                acc[1][0] += a4.y*b4.x; acc[1][1] += a4.y*b4.y; acc[1][2] += a4.y*b4.z; acc[1][3] += a4.y*b4.w;
                acc[2][0] += a4.z*b4.x; acc[2][1] += a4.z*b4.y; acc[2][2] += a4.z*b4.z; acc[2][3] += a4.z*b4.w;
                acc[3][0] += a4.w*b4.x; acc[3][1] += a4.w*b4.y; acc[3][2] += a4.w*b4.z; acc[3][3] += a4.w*b4.w;
            }
            __syncthreads();
        }
        int col = tx * 4;
        #pragma unroll
        for (int i = 0; i < 4; ++i) {
            int row = rowBase + ty * 4 + i;
            f16x4 hv, lv;
            #pragma unroll
            for (int c = 0; c < 4; ++c) {
                float v = acc[i][c];
                f16 h = (f16)v;
                hv[c] = h;
                lv[c] = (f16)((v - (float)h) * LO_SCALE);
            }
            if (bx < 4) {
                int cg = nBase + col;
                int head = cg >> 5, dv = cg & 31;
                int b2 = row >> 10, i2 = row & 1023;
                size_t off = ((size_t)(b2 * 8 + head) * 1024 + i2) * 32 + dv;
                *(f16x4*)(khi + off) = hv;
                *(f16x4*)(klo + off) = lv;
            } else if (col < 32) {
                *(f16x4*)(qhi + (size_t)row * 32 + col) = hv;
                *(f16x4*)(qlo + (size_t)row * 32 + col) = lv;
            }
        }
    } else {
        // ---- V bf16 MFMA GEMM (exact R16 k_gemmV; smem as [2][4096]x2)
        unsigned short* AsV = (unsigned short*)smem;            // [2][4096]
        unsigned short* BsV = (unsigned short*)(smem + 16384);  // [2][4096]
        int vid = bid - 640;
        int rowBase = (vid & 127) * 64, colBase = (vid >> 7) * 64;
        int l = t & 63, w = t >> 6, wr = w >> 1, wc = w & 1;
        int r0 = t >> 3,        c0 = t & 7;
        int r1 = (t + 256) >> 3, c1 = t & 7;
        int s0 = (r0 * 8 + (c0 ^ (r0 & 7))) * 8;
        int s1 = (r1 * 8 + (c1 ^ (r1 & 7))) * 8;
        f32x4 acc00 = {0.f,0.f,0.f,0.f}, acc01 = acc00, acc10 = acc00, acc11 = acc00;
        int m = l & 15, g2 = l >> 4;
        int swm = m & 7;
        {
            uint4 va0 = *(const uint4*)(Abf + (size_t)(rowBase + r0) * 256 + c0 * 8);
            uint4 va1 = *(const uint4*)(Abf + (size_t)(rowBase + r1) * 256 + c1 * 8);
            uint4 vb0 = *(const uint4*)(Bt  + (size_t)(colBase + r0) * 256 + c0 * 8);
            uint4 vb1 = *(const uint4*)(Bt  + (size_t)(colBase + r1) * 256 + c1 * 8);
            *(uint4*)&AsV[s0] = va0; *(uint4*)&AsV[s1] = va1;
            *(uint4*)&BsV[s0] = vb0; *(uint4*)&BsV[s1] = vb1;
        }
        __syncthreads();
        int cur = 0;
        for (int kt = 0; kt < 4; ++kt) {
            uint4 va0, va1, vb0, vb1;
            bool pf = (kt + 1) < 4;
            if (pf) {
                int k0 = (kt + 1) * 64;
                va0 = *(const uint4*)(Abf + (size_t)(rowBase + r0) * 256 + k0 + c0 * 8);
                va1 = *(const uint4*)(Abf + (size_t)(rowBase + r1) * 256 + k0 + c1 * 8);
                vb0 = *(const uint4*)(Bt  + (size_t)(colBase + r0) * 256 + k0 + c0 * 8);
                vb1 = *(const uint4*)(Bt  + (size_t)(colBase + r1) * 256 + k0 + c1 * 8);
            }
            #pragma unroll
            for (int ks = 0; ks < 2; ++ks) {
                int kc = ks * 4 + g2;
                int sc = kc ^ swm;
                s16x8 a0 = *(const s16x8*)&AsV[cur * 4096 + ((wr*32      + m) * 8 + sc) * 8];
                s16x8 a1 = *(const s16x8*)&AsV[cur * 4096 + ((wr*32 + 16 + m) * 8 + sc) * 8];
                s16x8 b0 = *(const s16x8*)&BsV[cur * 4096 + ((wc*32      + m) * 8 + sc) * 8];
                s16x8 b1 = *(const s16x8*)&BsV[cur * 4096 + ((wc*32 + 16 + m) * 8 + sc) * 8];
                acc00 = __builtin_amdgcn_mfma_f32_16x16x32_bf16(a0, b0, acc00, 0, 0, 0);
                acc01 = __builtin_amdgcn_mfma_f32_16x16x32_bf16(a0, b1, acc01, 0, 0, 0);
                acc10 = __builtin_amdgcn_mfma_f32_16x16x32_bf16(a1, b0, acc10, 0, 0, 0);
                acc11 = __builtin_amdgcn_mfma_f32_16x16x32_bf16(a1, b1, acc11, 0, 0, 0);
            }
            if (pf) {
                *(uint4*)&AsV[(cur ^ 1) * 4096 + s0] = va0;
                *(uint4*)&AsV[(cur ^ 1) * 4096 + s1] = va1;
                *(uint4*)&BsV[(cur ^ 1) * 4096 + s0] = vb0;
                *(uint4*)&BsV[(cur ^ 1) * 4096 + s1] = vb1;
            }
            __syncthreads();
            cur ^= 1;
        }
        #pragma unroll
        for (int fr = 0; fr < 2; ++fr) {
            #pragma unroll
            for (int fc = 0; fc < 2; ++fc) {
                f32x4 Acc = fr == 0 ? (fc == 0 ? acc00 : acc01)
                                    : (fc == 0 ? acc10 : acc11);
                int col = colBase + wc * 32 + fc * 16 + m;
                #pragma unroll
                for (int rr = 0; rr < 4; ++rr) {
                    int row = rowBase + wr * 32 + fr * 16 + g2 * 4 + rr;
                    V[(size_t)row * 256 + col] = f2bf(Acc[rr]);
                }
            }
        }
    }
}

// ------------------------------------------------- scores argmax (fp16x2 MFMA)
__global__ __launch_bounds__(256) void k_argmax(const f16* __restrict__ qhi_g,
        const f16* __restrict__ qlo_g, const f16* __restrict__ khi_g,
        const f16* __restrict__ klo_g, float* __restrict__ valp,
        int* __restrict__ idxp) {
    __shared__ float mval[2][64];
    __shared__ int   midx[2][64];
    int t = threadIdx.x;
    int bid = blockIdx.x;
    int grp = bid & 63;
    int rest = bid >> 6;            // 0..31
    int itile = rest >> 1, jh = rest & 1;
    int h = grp & 7, b = grp >> 3;
    int i0 = itile * 64;
    int w = t >> 6, l = t & 63, m = l & 15, g = l >> 4;
    int iw = w & 1, jq = w >> 1;
    int ibase = i0 + iw * 32;
    int jbase = jh * 512 + jq * 256;
    f16x8 qh0 = *(const f16x8*)(qhi_g + (size_t)(b * N_ + ibase + m) * 32 + g * 8);
    f16x8 ql0 = *(const f16x8*)(qlo_g + (size_t)(b * N_ + ibase + m) * 32 + g * 8);
    f16x8 qh1 = *(const f16x8*)(qhi_g + (size_t)(b * N_ + ibase + 16 + m) * 32 + g * 8);
    f16x8 ql1 = *(const f16x8*)(qlo_g + (size_t)(b * N_ + ibase + 16 + m) * 32 + g * 8);
    const f16* ph = khi_g + ((size_t)(b * H_ + h) * N_ + jbase + m) * 32 + g * 8;
    const f16* pl = klo_g + ((size_t)(b * H_ + h) * N_ + jbase + m) * 32 + g * 8;
    float best0[4] = {-3e38f, -3e38f, -3e38f, -3e38f};
    float best1[4] = {-3e38f, -3e38f, -3e38f, -3e38f};
    int   bj0[4] = {0,0,0,0}, bj1[4] = {0,0,0,0};
    f16x8 bh = *(const f16x8*)ph;
    f16x8 bl = *(const f16x8*)pl;
    #pragma unroll 2
    for (int jt = 0; jt < 16; ++jt) {
        f16x8 nh, nl;
        if (jt < 15) {
            nh = *(const f16x8*)(ph + (size_t)(jt + 1) * 512);
            nl = *(const f16x8*)(pl + (size_t)(jt + 1) * 512);
        }
        f32x4 z = {0.f, 0.f, 0.f, 0.f};
        f32x4 ah0 = __builtin_amdgcn_mfma_f32_16x16x32_f16(qh0, bh, z, 0, 0, 0);
        f32x4 ax0 = __builtin_amdgcn_mfma_f32_16x16x32_f16(qh0, bl, z, 0, 0, 0);
        ax0 = __builtin_amdgcn_mfma_f32_16x16x32_f16(ql0, bh, ax0, 0, 0, 0);
        f32x4 al0 = __builtin_amdgcn_mfma_f32_16x16x32_f16(ql0, bl, z, 0, 0, 0);
        f32x4 ah1 = __builtin_amdgcn_mfma_f32_16x16x32_f16(qh1, bh, z, 0, 0, 0);
        f32x4 ax1 = __builtin_amdgcn_mfma_f32_16x16x32_f16(qh1, bl, z, 0, 0, 0);
        ax1 = __builtin_amdgcn_mfma_f32_16x16x32_f16(ql1, bh, ax1, 0, 0, 0);
        f32x4 al1 = __builtin_amdgcn_mfma_f32_16x16x32_f16(ql1, bl, z, 0, 0, 0);
        int jg = jbase + jt * 16 + m;
        #pragma unroll
        for (int r = 0; r < 4; ++r) {
            float s0v = ah0[r] + ax0[r] * INV_LO + al0[r] * INV_LO2;
            if (s0v > best0[r]) { best0[r] = s0v; bj0[r] = jg; }
            float s1v = ah1[r] + ax1[r] * INV_LO + al1[r] * INV_LO2;
            if (s1v > best1[r]) { best1[r] = s1v; bj1[r] = jg; }
        }
        bh = nh; bl = nl;
    }
    #pragma unroll
    for (int off = 1; off < 16; off <<= 1) {
        #pragma unroll
        for (int r = 0; r < 4; ++r) {
            float ov = __shfl_xor(best0[r], off);
            int   oj = __shfl_xor(bj0[r], off);
            if (ov > best0[r] || (ov == best0[r] && oj < bj0[r])) {
                best0[r] = ov; bj0[r] = oj;
            }
            float ov1 = __shfl_xor(best1[r], off);
            int   oj1 = __shfl_xor(bj1[r], off);
            if (ov1 > best1[r] || (ov1 == best1[r] && oj1 < bj1[r])) {
                best1[r] = ov1; bj1[r] = oj1;
            }
        }
    }
    if (m == 0) {
        #pragma unroll
        for (int r = 0; r < 4; ++r) {
            mval[jq][iw * 32 + g * 4 + r]      = best0[r];
            midx[jq][iw * 32 + g * 4 + r]      = bj0[r];
            mval[jq][iw * 32 + 16 + g * 4 + r] = best1[r];
            midx[jq][iw * 32 + 16 + g * 4 + r] = bj1[r];
        }
    }
    __syncthreads();
    if (t < 64) {
        float v0 = mval[0][t]; int j0 = midx[0][t];
        float v1 = mval[1][t]; int j1 = midx[1][t];
        float v = (v1 > v0) ? v1 : v0;
        int   j = (v1 > v0) ? j1 : j0;
        int o = (b * H_ + h) * N_ + i0 + t;
        valp[jh * 65536 + o] = v;
        idxp[jh * 65536 + o] = j;
    }
}

// ------------------------------------------------- gather + LN(32) + head-sum
__global__ __launch_bounds__(256) void k_hsum(const unsigned short* __restrict__ vbf,
        const float* __restrict__ valp, const int* __restrict__ idxp,
        const float* __restrict__ res, const float* __restrict__ g,
        const float* __restrict__ bb, unsigned short* __restrict__ u) {
    __shared__ float rel[32][8][33];
    int t = threadIdx.x;
    int rowBase = blockIdx.x * 32;
    int rw = t >> 3, h = t & 7;
    int bn = rowBase + rw;
    int b = bn >> 10, i = bn & 1023;
    int o = (b * H_ + h) * N_ + i;
    float v0 = valp[o], v1 = valp[65536 + o];
    int j = (v1 > v0) ? idxp[65536 + o] : idxp[o];
    const uint4* src = (const uint4*)(vbf + (size_t)(b * N_ + j) * 256 + h * 32);
    float v[32];
    #pragma unroll
    for (int c = 0; c < 4; ++c) {
        uint4 uu = src[c];
        v[c*8+0] = bf2f((unsigned short)(uu.x & 0xffff));
        v[c*8+1] = bf2f((unsigned short)(uu.x >> 16));
        v[c*8+2] = bf2f((unsigned short)(uu.y & 0xffff));
        v[c*8+3] = bf2f((unsigned short)(uu.y >> 16));
        v[c*8+4] = bf2f((unsigned short)(uu.z & 0xffff));
        v[c*8+5] = bf2f((unsigned short)(uu.z >> 16));
        v[c*8+6] = bf2f((unsigned short)(uu.w & 0xffff));
        v[c*8+7] = bf2f((unsigned short)(uu.w >> 16));
    }
    float s = 0.f, sq = 0.f;
    #pragma unroll
    for (int d = 0; d < 32; ++d) { s += v[d]; sq += v[d]*v[d]; }
    float m = s * (1.f/32.f), var = sq * (1.f/32.f) - m * m;
    float rs = rsqrtf(var + 1e-5f);
    #pragma unroll
    for (int d = 0; d < 32; ++d)
        rel[rw][h][d] = (v[d] - m) * rs * g[d] + bb[d];
    __syncthreads();
    #pragma unroll
    for (int e = t; e < 1024; e += 256) {
        int r = e >> 5, d = e & 31;
        float acc = 0.f;
        #pragma unroll
        for (int hh = 0; hh < 8; ++hh) acc += rel[r][hh][d];
        u[(rowBase + r) * 64 + d]      = f2bf(acc);
        u[(rowBase + r) * 64 + 32 + d] = f2bf(8.f * res[(rowBase + r) * 32 + d]);
    }
}

// ------------------------------------------------- mid = gelu(u @ w_inner + 8*b_inner)
__global__ __launch_bounds__(256) void k_mid(const unsigned short* __restrict__ u,
        const unsigned short* __restrict__ wiT, const float* __restrict__ b_inner,
        unsigned short* __restrict__ mid) {
    __shared__ __align__(16) unsigned short As[4096];
    __shared__ __align__(16) unsigned short Bs[4096];
    int t = threadIdx.x;
    int rowBase = blockIdx.x * 64, colBase = blockIdx.y * 64;
    int l = t & 63, w = t >> 6, wr = w >> 1, wc = w & 1;
    int r = t >> 2, cA = (t & 3) * 2;
    {
        uint4 a0 = *(const uint4*)(u   + (size_t)(rowBase + r) * 64 + cA * 8);
        uint4 a1 = *(const uint4*)(u   + (size_t)(rowBase + r) * 64 + cA * 8 + 8);
        uint4 b0 = *(const uint4*)(wiT + (size_t)(colBase + r) * 64 + cA * 8);
        uint4 b1 = *(const uint4*)(wiT + (size_t)(colBase + r) * 64 + cA * 8 + 8);
        *(uint4*)&As[(r * 8 + ( cA      ^ (r & 7))) * 8] = a0;
        *(uint4*)&As[(r * 8 + ((cA + 1) ^ (r & 7))) * 8] = a1;
        *(uint4*)&Bs[(r * 8 + ( cA      ^ (r & 7))) * 8] = b0;
        *(uint4*)&Bs[(r * 8 + ((cA + 1) ^ (r & 7))) * 8] = b1;
    }
    __syncthreads();
    f32x4 acc00 = {0.f,0.f,0.f,0.f}, acc01 = acc00, acc10 = acc00, acc11 = acc00;
    int m = l & 15, g = l >> 4;
    int swm = m & 7;
    #pragma unroll
    for (int ks = 0; ks < 2; ++ks) {
        int kc = ks * 4 + g;
        int sc = kc ^ swm;
        s16x8 a0 = *(const s16x8*)&As[((wr*32      + m) * 8 + sc) * 8];
        s16x8 a1 = *(const s16x8*)&As[((wr*32 + 16 + m) * 8 + sc) * 8];
        s16x8 b0 = *(const s16x8*)&Bs[((wc*32      + m) * 8 + sc) * 8];
        s16x8 b1 = *(const s16x8*)&Bs[((wc*32 + 16 + m) * 8 + sc) * 8];
        acc00 = __builtin_amdgcn_mfma_f32_16x16x32_bf16(a0, b0, acc00, 0, 0, 0);
        acc01 = __builtin_amdgcn_mfma_f32_16x16x32_bf16(a0, b1, acc01, 0, 0, 0);
        acc10 = __builtin_amdgcn_mfma_f32_16x16x32_bf16(a1, b0, acc10, 0, 0, 0);
        acc11 = __builtin_amdgcn_mfma_f32_16x16x32_bf16(a1, b1, acc11, 0, 0, 0);
    }
    #pragma unroll
    for (int fr = 0; fr < 2; ++fr) {
        #pragma unroll
        for (int fc = 0; fc < 2; ++fc) {
            f32x4 A = fr == 0 ? (fc == 0 ? acc00 : acc01)
                              : (fc == 0 ? acc10 : acc11);
            int col = colBase + wc * 32 + fc * 16 + m;
            float bi = 8.f * b_inner[col];
            #pragma unroll
            for (int rr = 0; rr < 4; ++rr) {
                int row = rowBase + wr * 32 + fr * 16 + g * 4 + rr;
                mid[(size_t)row * HID_ + col] = f2bf(gelu(A[rr] + bi));
            }
        }
    }
}

// ------------------------------------------------- out = mid @ w_outer + b_outer + x
__global__ __launch_bounds__(256) void k_out(const unsigned short* __restrict__ mid,
        const unsigned short* __restrict__ woT, const float* __restrict__ b_outer,
        const float* __restrict__ x, float* __restrict__ out) {
    __shared__ __align__(16) unsigned short As[2][4096];
    __shared__ __align__(16) unsigned short Bs[2][4096];
    int t = threadIdx.x;
    int rowBase = blockIdx.x * 64, colBase = blockIdx.y * 64;
    int l = t & 63, w = t >> 6, wr = w >> 1, wc = w & 1;
    int r0 = t >> 3,        c0 = t & 7;
    int r1 = (t + 256) >> 3, c1 = t & 7;
    int s0 = (r0 * 8 + (c0 ^ (r0 & 7))) * 8;
    int s1 = (r1 * 8 + (c1 ^ (r1 & 7))) * 8;
    f32x4 acc00 = {0.f,0.f,0.f,0.f}, acc01 = acc00, acc10 = acc00, acc11 = acc00;
    int m = l & 15, g = l >> 4;
    int swm = m & 7;
    {
        uint4 va0 = *(const uint4*)(mid + (size_t)(rowBase + r0) * 1024 + c0 * 8);
        uint4 va1 = *(const uint4*)(mid + (size_t)(rowBase + r1) * 1024 + c1 * 8);
        uint4 vb0 = *(const uint4*)(woT + (size_t)(colBase + r0) * 1024 + c0 * 8);
        uint4 vb1 = *(const uint4*)(woT + (size_t)(colBase + r1) * 1024 + c1 * 8);
        *(uint4*)&As[0][s0] = va0; *(uint4*)&As[0][s1] = va1;
        *(uint4*)&Bs[0][s0] = vb0; *(uint4*)&Bs[0][s1] = vb1;
    }
    __syncthreads();
    int cur = 0;
    for (int kt = 0; kt < 16; ++kt) {
        uint4 va0, va1, vb0, vb1;
        bool pf = (kt + 1) < 16;
        if (pf) {
            int k0 = (kt + 1) * 64;
            va0 = *(const uint4*)(mid + (size_t)(rowBase + r0) * 1024 + k0 + c0 * 8);
            va1 = *(const uint4*)(mid + (size_t)(rowBase + r1) * 1024 + k0 + c1 * 8);
            vb0 = *(const uint4*)(woT + (size_t)(colBase + r0) * 1024 + k0 + c0 * 8);
            vb1 = *(const uint4*)(woT + (size_t)(colBase + r1) * 1024 + k0 + c1 * 8);
        }
        #pragma unroll
        for (int ks = 0; ks < 2; ++ks) {
            int kc = ks * 4 + g;
            int sc = kc ^ swm;
            s16x8 a0 = *(const s16x8*)&As[cur][((wr*32      + m) * 8 + sc) * 8];
            s16x8 a1 = *(const s16x8*)&As[cur][((wr*32 + 16 + m) * 8 + sc) * 8];
            s16x8 b0 = *(const s16x8*)&Bs[cur][((wc*32      + m) * 8 + sc) * 8];
            s16x8 b1 = *(const s16x8*)&Bs[cur][((wc*32 + 16 + m) * 8 + sc) * 8];
            acc00 = __builtin_amdgcn_mfma_f32_16x16x32_bf16(a0, b0, acc00, 0, 0, 0);
            acc01 = __builtin_amdgcn_mfma_f32_16x16x32_bf16(a0, b1, acc01, 0, 0, 0);
            acc10 = __builtin_amdgcn_mfma_f32_16x16x32_bf16(a1, b0, acc10, 0, 0, 0);
            acc11 = __builtin_amdgcn_mfma_f32_16x16x32_bf16(a1, b1, acc11, 0, 0, 0);
        }
        if (pf) {
            *(uint4*)&As[cur ^ 1][s0] = va0; *(uint4*)&As[cur ^ 1][s1] = va1;
            *(uint4*)&Bs[cur ^ 1][s0] = vb0; *(uint4*)&Bs[cur ^ 1][s1] = vb1;
        }
        __syncthreads();
        cur ^= 1;
    }
    #pragma unroll
    for (int fr = 0; fr < 2; ++fr) {
        #pragma unroll
        for (int fc = 0; fc < 2; ++fc) {
            f32x4 A = fr == 0 ? (fc == 0 ? acc00 : acc01)
                              : (fc == 0 ? acc10 : acc11);
            int col = colBase + wc * 32 + fc * 16 + m;
            float bo = b_outer[col];
            #pragma unroll
            for (int rr = 0; rr < 4; ++rr) {
                int row = rowBase + wr * 32 + fr * 16 + g * 4 + rr;
                out[(size_t)row * 256 + col] = A[rr] + bo + x[(size_t)row * 256 + col];
            }
        }
    }
}

extern "C" void kernel_launch(void* const* d_in, const int* in_sizes, int n_in,
                              void* d_out, int out_size, void* d_ws, size_t ws_size,
                              hipStream_t stream) {
    const float* x        = (const float*)d_in[0];
    const float* w_q      = (const float*)d_in[1];
    const float* w_kv     = (const float*)d_in[2];
    const float* ln_out_g = (const float*)d_in[3];
    const float* ln_out_b = (const float*)d_in[4];
    const float* ln_rel_g = (const float*)d_in[5];
    const float* ln_rel_b = (const float*)d_in[6];
    const float* w_down   = (const float*)d_in[7];
    const float* b_down   = (const float*)d_in[8];
    const float* w_inner  = (const float*)d_in[9];
    const float* b_inner  = (const float*)d_in[10];
    const float* w_outer  = (const float*)d_in[11];
    const float* b_outer  = (const float*)d_in[12];
    float* out = (float*)d_out;

    float* ws = (float*)d_ws;
    float* pre = ws;                                          // [0, 2,097,152)
    unsigned short* pbf = (unsigned short*)(ws + 2097152);    // -> 3,145,728
    f16* khi = (f16*)(ws + 3145728);                          // -> 4,194,304
    f16* klo = (f16*)(ws + 4194304);                          // -> 5,242,880
    unsigned short* vbf = (unsigned short*)(ws + 5242880);    // -> 6,291,456
    f16* qhi = (f16*)(ws + 6291456);                          // -> 6,422,528
    f16* qlo = (f16*)(ws + 6422528);                          // -> 6,553,600
    float* resbuf = ws + 6553600;                             // -> 6,815,744
    unsigned short* ubuf = (unsigned short*)(ws + 6815744);   // -> 7,077,888
    float* valp = ws + 7077888;                               // -> 7,208,960
    int* idxp = (int*)(ws + 7208960);                         // -> 7,340,032
    unsigned short* woT = (unsigned short*)(ws + 7340032);    // -> 7,471,104
    unsigned short* wiT = (unsigned short*)(ws + 7471104);    // -> 7,503,872
    unsigned short* wvT = ubuf;            // alias: dead before k_hsum writes ubuf
    unsigned short* mid = (unsigned short*)ws;  // aliases pre/pbf/khi (dead by k_mid)

    k_front<<<2272, 256, 0, stream>>>(x, ln_out_g, ln_out_b, w_down, b_down,
                                      w_kv, w_outer, w_inner,
                                      pre, pbf, resbuf, wvT, woT, wiT);
    k_gemms<<<1152, 256, 0, stream>>>(pre, pbf, w_kv, w_q, wvT,
                                      khi, klo, qhi, qlo, vbf);
    k_argmax<<<2048, 256, 0, stream>>>(qhi, qlo, khi, klo, valp, idxp);
    k_hsum<<<256, 256, 0, stream>>>(vbf, valp, idxp, resbuf, ln_rel_g, ln_rel_b, ubuf);
    k_mid<<<dim3(128, 16), 256, 0, stream>>>(ubuf, wiT, b_inner, mid);
    k_out<<<dim3(128, 4), 256, 0, stream>>>(mid, woT, b_outer, x, out);
}

// Round 18
// 121.725 us; speedup vs baseline: 1.0464x; 1.0464x over previous
//
#include <hip/hip_runtime.h>
#include <math.h>

#define D_    256
#define N_    1024
#define B_    8
#define H_    8
#define DV_   32
#define HID_  1024
#define ROWS_ (B_*N_)   // 8192

typedef _Float16 f16;
typedef __attribute__((ext_vector_type(8))) _Float16 f16x8;
typedef __attribute__((ext_vector_type(4))) _Float16 f16x4;
typedef __attribute__((ext_vector_type(8))) short s16x8;
typedef __attribute__((ext_vector_type(4))) float f32x4;

#define LO_SCALE   2048.0f          // 2^11: lifts lo plane out of f16 subnormal range
#define INV_LO     (1.0f/2048.0f)
#define INV_LO2    (1.0f/4194304.0f)

__device__ __forceinline__ unsigned short f2bf(float f) {
    unsigned u = __float_as_uint(f);
    unsigned r = (u + 0x7fffu + ((u >> 16) & 1u)) >> 16;
    return (unsigned short)r;
}
__device__ __forceinline__ float bf2f(unsigned short u) {
    return __uint_as_float((unsigned)u << 16);
}

// fast erf (Abramowitz-Stegun 7.1.26, |err| < 1.5e-7)
__device__ __forceinline__ float erf_fast(float x) {
    float ax = fabsf(x);
    float t = 1.f / (1.f + 0.3275911f * ax);
    float y = ((((1.061405429f * t - 1.453152027f) * t + 1.421413741f) * t
                - 0.284496736f) * t + 0.254829592f) * t;
    float e = __expf(-ax * ax);
    float r = 1.f - y * e;
    return x < 0.f ? -r : r;
}
__device__ __forceinline__ float gelu(float v) {
    return 0.5f * v * (1.f + erf_fast(v * 0.70710678118f));
}

// ---------------------------------------- LayerNorm -> fp32 pre + bf16 copy
__global__ __launch_bounds__(256) void k_ln(const float* __restrict__ x,
        const float* __restrict__ g, const float* __restrict__ b,
        float* __restrict__ pre, unsigned short* __restrict__ pbf) {
    int t = threadIdx.x;
    int lane = t & 63;
    int row = blockIdx.x * 4 + (t >> 6);
    const float4 v = ((const float4*)(x + row * D_))[lane];
    float s  = v.x + v.y + v.z + v.w;
    float sq = v.x*v.x + v.y*v.y + v.z*v.z + v.w*v.w;
    #pragma unroll
    for (int o = 32; o; o >>= 1) { s += __shfl_xor(s, o); sq += __shfl_xor(sq, o); }
    float m   = s * (1.0f / D_);
    float var = sq * (1.0f / D_) - m * m;
    float rs  = rsqrtf(var + 1e-5f);
    const float4 gv = ((const float4*)g)[lane];
    const float4 bv = ((const float4*)b)[lane];
    float4 o;
    o.x = (v.x - m) * rs * gv.x + bv.x;
    o.y = (v.y - m) * rs * gv.y + bv.y;
    o.z = (v.z - m) * rs * gv.z + bv.z;
    o.w = (v.w - m) * rs * gv.w + bv.w;
    ((float4*)(pre + row * D_))[lane] = o;
    ushort4 u4;
    u4.x = f2bf(o.x); u4.y = f2bf(o.y); u4.z = f2bf(o.z); u4.w = f2bf(o.w);
    *(ushort4*)(pbf + (size_t)row * D_ + lane * 4) = u4;
}

// ------------- merged prep: res GEMM (blocks 0-127) + 3 transposes (128-223)
__global__ __launch_bounds__(256) void k_prep(const float* __restrict__ x,
        const float* __restrict__ w_down, const float* __restrict__ b_down,
        const float* __restrict__ w_kv, const float* __restrict__ w_outer,
        const float* __restrict__ w_inner, float* __restrict__ resbuf,
        unsigned short* __restrict__ wvT, unsigned short* __restrict__ woT,
        unsigned short* __restrict__ wiT) {
    __shared__ float smem[64 * 65];
    int t = threadIdx.x;
    int bid = blockIdx.x;
    if (bid < 128) {
        float (*As)[64] = (float(*)[64])smem;
        float (*Bs)[64] = (float(*)[64])(smem + 16 * 64);
        int rowBase = bid * 64;
        int tx = t & 15, ty = t >> 4;
        int arow = t >> 2, ak = (t & 3) * 4;
        int bk = t >> 4, bn = (t & 15) * 4;
        float acc[4][4] = {};
        for (int kt = 0; kt < 256; kt += 16) {
            float4 av = *(const float4*)(x + (rowBase + arow) * 256 + kt + ak);
            As[ak+0][arow] = av.x; As[ak+1][arow] = av.y;
            As[ak+2][arow] = av.z; As[ak+3][arow] = av.w;
            float4 bv = make_float4(0.f, 0.f, 0.f, 0.f);
            if (bn < 32)
                bv = *(const float4*)(w_down + (kt + bk) * 32 + bn);
            *(float4*)&Bs[bk][bn] = bv;
            __syncthreads();
            #pragma unroll
            for (int kk = 0; kk < 16; ++kk) {
                float4 a4 = *(const float4*)&As[kk][ty*4];
                float4 b4 = *(const float4*)&Bs[kk][tx*4];
                acc[0][0] += a4.x*b4.x; acc[0][1] += a4.x*b4.y; acc[0][2] += a4.x*b4.z; acc[0][3] += a4.x*b4.w;
                acc[1][0] += a4.y*b4.x; acc[1][1] += a4.y*b4.y; acc[1][2] += a4.y*b4.z; acc[1][3] += a4.y*b4.w;
                acc[2][0] += a4.z*b4.x; acc[2][1] += a4.z*b4.y; acc[2][2] += a4.z*b4.z; acc[2][3] += a4.z*b4.w;
                acc[3][0] += a4.w*b4.x; acc[3][1] += a4.w*b4.y; acc[3][2] += a4.w*b4.z; acc[3][3] += a4.w*b4.w;
            }
            __syncthreads();
        }
        int col = tx * 4;
        if (col < 32) {
            float4 bb = *(const float4*)(b_down + col);
            #pragma unroll
            for (int i = 0; i < 4; ++i) {
                float4 o;
                o.x = acc[i][0] + bb.x; o.y = acc[i][1] + bb.y;
                o.z = acc[i][2] + bb.z; o.w = acc[i][3] + bb.w;
                *(float4*)(resbuf + (rowBase + ty*4 + i) * 32 + col) = o;
            }
        }
    } else {
        const float* src; unsigned short* dst;
        int srcCols, dstCols, r0, c0;
        if (bid < 144) {
            int s2 = bid - 128;
            src = w_kv + 256; dst = wvT; srcCols = 512; dstCols = 256;
            r0 = (s2 >> 2) * 64; c0 = (s2 & 3) * 64;
        } else if (bid < 208) {
            int s2 = bid - 144;
            src = w_outer; dst = woT; srcCols = 256; dstCols = 1024;
            r0 = (s2 >> 2) * 64; c0 = (s2 & 3) * 64;
        } else {
            int s2 = bid - 208;
            src = w_inner; dst = wiT; srcCols = 1024; dstCols = 64;
            r0 = 0; c0 = s2 * 64;
        }
        float (*t64)[65] = (float(*)[65])smem;
        #pragma unroll
        for (int e = t; e < 4096; e += 256) {
            int r = e >> 6, c = e & 63;
            t64[r][c] = src[(size_t)(r0 + r) * srcCols + c0 + c];
        }
        __syncthreads();
        #pragma unroll
        for (int e = t; e < 4096; e += 256) {
            int c = e >> 6, r = e & 63;
            dst[(size_t)(c0 + c) * dstCols + r0 + r] = f2bf(t64[r][c]);
        }
    }
}

// ---------------- K|q = pre @ [w_kv[:,:256] | w_q] fp32, epilogue -> hi/lo f16
// K written HEAD-MAJOR: khi/klo[((b*8+head)*1024 + i)*32 + dv]
__global__ __launch_bounds__(256) void k_gemmK(const float* __restrict__ A,
        const float* __restrict__ Bm, const float* __restrict__ Bq,
        f16* __restrict__ khi, f16* __restrict__ klo,
        f16* __restrict__ qhi, f16* __restrict__ qlo) {
    __shared__ float As[16][64];
    __shared__ float Bs[16][64];
    int t = threadIdx.x;
    int bx = blockIdx.x;
    int nBase = bx * 64, rowBase = blockIdx.y * 64;
    int tx = t & 15, ty = t >> 4;
    int arow = t >> 2, ak = (t & 3) * 4;
    int bk = t >> 4, bn = (t & 15) * 4;
    float acc[4][4] = {};
    for (int kt = 0; kt < 256; kt += 16) {
        float4 av = *(const float4*)(A + (rowBase + arow) * 256 + kt + ak);
        As[ak+0][arow] = av.x; As[ak+1][arow] = av.y;
        As[ak+2][arow] = av.z; As[ak+3][arow] = av.w;
        float4 bv = make_float4(0.f, 0.f, 0.f, 0.f);
        if (bx < 4)
            bv = *(const float4*)(Bm + (size_t)(kt + bk) * 512 + nBase + bn);
        else if (bn < 32)
            bv = *(const float4*)(Bq + (size_t)(kt + bk) * 32 + bn);
        *(float4*)&Bs[bk][bn] = bv;
        __syncthreads();
        #pragma unroll
        for (int kk = 0; kk < 16; ++kk) {
            float4 a4 = *(const float4*)&As[kk][ty*4];
            float4 b4 = *(const float4*)&Bs[kk][tx*4];
            acc[0][0] += a4.x*b4.x; acc[0][1] += a4.x*b4.y; acc[0][2] += a4.x*b4.z; acc[0][3] += a4.x*b4.w;
            acc[1][0] += a4.y*b4.x; acc[1][1] += a4.y*b4.y; acc[1][2] += a4.y*b4.z; acc[1][3] += a4.y*b4.w;
            acc[2][0] += a4.z*b4.x; acc[2][1] += a4.z*b4.y; acc[2][2] += a4.z*b4.z; acc[2][3] += a4.z*b4.w;
            acc[3][0] += a4.w*b4.x; acc[3][1] += a4.w*b4.y; acc[3][2] += a4.w*b4.z; acc[3][3] += a4.w*b4.w;
        }
        __syncthreads();
    }
    int col = tx * 4;
    #pragma unroll
    for (int i = 0; i < 4; ++i) {
        int row = rowBase + ty * 4 + i;
        f16x4 hv, lv;
        #pragma unroll
        for (int c = 0; c < 4; ++c) {
            float v = acc[i][c];
            f16 h = (f16)v;
            hv[c] = h;
            lv[c] = (f16)((v - (float)h) * LO_SCALE);
        }
        if (bx < 4) {
            int cg = nBase + col;
            int head = cg >> 5, dv = cg & 31;
            int b2 = row >> 10, i2 = row & 1023;
            size_t off = ((size_t)(b2 * 8 + head) * 1024 + i2) * 32 + dv;
            *(f16x4*)(khi + off) = hv;
            *(f16x4*)(klo + off) = lv;
        } else if (col < 32) {
            *(f16x4*)(qhi + (size_t)row * 32 + col) = hv;
            *(f16x4*)(qlo + (size_t)row * 32 + col) = lv;
        }
    }
}

// ------------------------- V = pbf @ wvT^T (bf16 MFMA, K=256) -> bf16
__global__ __launch_bounds__(256) void k_gemmV(const unsigned short* __restrict__ A,
        const unsigned short* __restrict__ Bt, unsigned short* __restrict__ V) {
    __shared__ __align__(16) unsigned short As[2][4096];
    __shared__ __align__(16) unsigned short Bs[2][4096];
    int t = threadIdx.x;
    int rowBase = blockIdx.x * 64, colBase = blockIdx.y * 64;
    int l = t & 63, w = t >> 6, wr = w >> 1, wc = w & 1;
    int r0 = t >> 3,        c0 = t & 7;
    int r1 = (t + 256) >> 3, c1 = t & 7;
    int s0 = (r0 * 8 + (c0 ^ (r0 & 7))) * 8;
    int s1 = (r1 * 8 + (c1 ^ (r1 & 7))) * 8;
    f32x4 acc00 = {0.f,0.f,0.f,0.f}, acc01 = acc00, acc10 = acc00, acc11 = acc00;
    int m = l & 15, g = l >> 4;
    int swm = m & 7;
    {
        uint4 va0 = *(const uint4*)(A  + (size_t)(rowBase + r0) * 256 + c0 * 8);
        uint4 va1 = *(const uint4*)(A  + (size_t)(rowBase + r1) * 256 + c1 * 8);
        uint4 vb0 = *(const uint4*)(Bt + (size_t)(colBase + r0) * 256 + c0 * 8);
        uint4 vb1 = *(const uint4*)(Bt + (size_t)(colBase + r1) * 256 + c1 * 8);
        *(uint4*)&As[0][s0] = va0; *(uint4*)&As[0][s1] = va1;
        *(uint4*)&Bs[0][s0] = vb0; *(uint4*)&Bs[0][s1] = vb1;
    }
    __syncthreads();
    int cur = 0;
    for (int kt = 0; kt < 4; ++kt) {
        uint4 va0, va1, vb0, vb1;
        bool pf = (kt + 1) < 4;
        if (pf) {
            int k0 = (kt + 1) * 64;
            va0 = *(const uint4*)(A  + (size_t)(rowBase + r0) * 256 + k0 + c0 * 8);
            va1 = *(const uint4*)(A  + (size_t)(rowBase + r1) * 256 + k0 + c1 * 8);
            vb0 = *(const uint4*)(Bt + (size_t)(colBase + r0) * 256 + k0 + c0 * 8);
            vb1 = *(const uint4*)(Bt + (size_t)(colBase + r1) * 256 + k0 + c1 * 8);
        }
        #pragma unroll
        for (int ks = 0; ks < 2; ++ks) {
            int kc = ks * 4 + g;
            int sc = kc ^ swm;
            s16x8 a0 = *(const s16x8*)&As[cur][((wr*32      + m) * 8 + sc) * 8];
            s16x8 a1 = *(const s16x8*)&As[cur][((wr*32 + 16 + m) * 8 + sc) * 8];
            s16x8 b0 = *(const s16x8*)&Bs[cur][((wc*32      + m) * 8 + sc) * 8];
            s16x8 b1 = *(const s16x8*)&Bs[cur][((wc*32 + 16 + m) * 8 + sc) * 8];
            acc00 = __builtin_amdgcn_mfma_f32_16x16x32_bf16(a0, b0, acc00, 0, 0, 0);
            acc01 = __builtin_amdgcn_mfma_f32_16x16x32_bf16(a0, b1, acc01, 0, 0, 0);
            acc10 = __builtin_amdgcn_mfma_f32_16x16x32_bf16(a1, b0, acc10, 0, 0, 0);
            acc11 = __builtin_amdgcn_mfma_f32_16x16x32_bf16(a1, b1, acc11, 0, 0, 0);
        }
        if (pf) {
            *(uint4*)&As[cur ^ 1][s0] = va0; *(uint4*)&As[cur ^ 1][s1] = va1;
            *(uint4*)&Bs[cur ^ 1][s0] = vb0; *(uint4*)&Bs[cur ^ 1][s1] = vb1;
        }
        __syncthreads();
        cur ^= 1;
    }
    #pragma unroll
    for (int fr = 0; fr < 2; ++fr) {
        #pragma unroll
        for (int fc = 0; fc < 2; ++fc) {
            f32x4 Acc = fr == 0 ? (fc == 0 ? acc00 : acc01)
                                : (fc == 0 ? acc10 : acc11);
            int col = colBase + wc * 32 + fc * 16 + m;
            #pragma unroll
            for (int rr = 0; rr < 4; ++rr) {
                int row = rowBase + wr * 32 + fr * 16 + g * 4 + rr;
                V[(size_t)row * 256 + col] = f2bf(Acc[rr]);
            }
        }
    }
}

// ------------------------------------------------- scores argmax (fp16x2 MFMA)
// R15 structure: head-major K, block j-split, partials merged in k_hsum.
__global__ __launch_bounds__(256) void k_argmax(const f16* __restrict__ qhi_g,
        const f16* __restrict__ qlo_g, const f16* __restrict__ khi_g,
        const f16* __restrict__ klo_g, float* __restrict__ valp,
        int* __restrict__ idxp) {
    __shared__ float mval[2][64];
    __shared__ int   midx[2][64];
    int t = threadIdx.x;
    int bid = blockIdx.x;
    int grp = bid & 63;
    int rest = bid >> 6;            // 0..31
    int itile = rest >> 1, jh = rest & 1;
    int h = grp & 7, b = grp >> 3;
    int i0 = itile * 64;
    int w = t >> 6, l = t & 63, m = l & 15, g = l >> 4;
    int iw = w & 1, jq = w >> 1;
    int ibase = i0 + iw * 32;
    int jbase = jh * 512 + jq * 256;
    f16x8 qh0 = *(const f16x8*)(qhi_g + (size_t)(b * N_ + ibase + m) * 32 + g * 8);
    f16x8 ql0 = *(const f16x8*)(qlo_g + (size_t)(b * N_ + ibase + m) * 32 + g * 8);
    f16x8 qh1 = *(const f16x8*)(qhi_g + (size_t)(b * N_ + ibase + 16 + m) * 32 + g * 8);
    f16x8 ql1 = *(const f16x8*)(qlo_g + (size_t)(b * N_ + ibase + 16 + m) * 32 + g * 8);
    const f16* ph = khi_g + ((size_t)(b * H_ + h) * N_ + jbase + m) * 32 + g * 8;
    const f16* pl = klo_g + ((size_t)(b * H_ + h) * N_ + jbase + m) * 32 + g * 8;
    float best0[4] = {-3e38f, -3e38f, -3e38f, -3e38f};
    float best1[4] = {-3e38f, -3e38f, -3e38f, -3e38f};
    int   bj0[4] = {0,0,0,0}, bj1[4] = {0,0,0,0};
    f16x8 bh = *(const f16x8*)ph;
    f16x8 bl = *(const f16x8*)pl;
    #pragma unroll 2
    for (int jt = 0; jt < 16; ++jt) {
        f16x8 nh, nl;
        if (jt < 15) {
            nh = *(const f16x8*)(ph + (size_t)(jt + 1) * 512);
            nl = *(const f16x8*)(pl + (size_t)(jt + 1) * 512);
        }
        f32x4 z = {0.f, 0.f, 0.f, 0.f};
        f32x4 ah0 = __builtin_amdgcn_mfma_f32_16x16x32_f16(qh0, bh, z, 0, 0, 0);
        f32x4 ax0 = __builtin_amdgcn_mfma_f32_16x16x32_f16(qh0, bl, z, 0, 0, 0);
        ax0 = __builtin_amdgcn_mfma_f32_16x16x32_f16(ql0, bh, ax0, 0, 0, 0);
        f32x4 al0 = __builtin_amdgcn_mfma_f32_16x16x32_f16(ql0, bl, z, 0, 0, 0);
        f32x4 ah1 = __builtin_amdgcn_mfma_f32_16x16x32_f16(qh1, bh, z, 0, 0, 0);
        f32x4 ax1 = __builtin_amdgcn_mfma_f32_16x16x32_f16(qh1, bl, z, 0, 0, 0);
        ax1 = __builtin_amdgcn_mfma_f32_16x16x32_f16(ql1, bh, ax1, 0, 0, 0);
        f32x4 al1 = __builtin_amdgcn_mfma_f32_16x16x32_f16(ql1, bl, z, 0, 0, 0);
        int jg = jbase + jt * 16 + m;
        #pragma unroll
        for (int r = 0; r < 4; ++r) {
            float s0v = ah0[r] + ax0[r] * INV_LO + al0[r] * INV_LO2;
            if (s0v > best0[r]) { best0[r] = s0v; bj0[r] = jg; }
            float s1v = ah1[r] + ax1[r] * INV_LO + al1[r] * INV_LO2;
            if (s1v > best1[r]) { best1[r] = s1v; bj1[r] = jg; }
        }
        bh = nh; bl = nl;
    }
    #pragma unroll
    for (int off = 1; off < 16; off <<= 1) {
        #pragma unroll
        for (int r = 0; r < 4; ++r) {
            float ov = __shfl_xor(best0[r], off);
            int   oj = __shfl_xor(bj0[r], off);
            if (ov > best0[r] || (ov == best0[r] && oj < bj0[r])) {
                best0[r] = ov; bj0[r] = oj;
            }
            float ov1 = __shfl_xor(best1[r], off);
            int   oj1 = __shfl_xor(bj1[r], off);
            if (ov1 > best1[r] || (ov1 == best1[r] && oj1 < bj1[r])) {
                best1[r] = ov1; bj1[r] = oj1;
            }
        }
    }
    if (m == 0) {
        #pragma unroll
        for (int r = 0; r < 4; ++r) {
            mval[jq][iw * 32 + g * 4 + r]      = best0[r];
            midx[jq][iw * 32 + g * 4 + r]      = bj0[r];
            mval[jq][iw * 32 + 16 + g * 4 + r] = best1[r];
            midx[jq][iw * 32 + 16 + g * 4 + r] = bj1[r];
        }
    }
    __syncthreads();
    if (t < 64) {
        float v0 = mval[0][t]; int j0 = midx[0][t];
        float v1 = mval[1][t]; int j1 = midx[1][t];
        float v = (v1 > v0) ? v1 : v0;
        int   j = (v1 > v0) ? j1 : j0;
        int o = (b * H_ + h) * N_ + i0 + t;
        valp[jh * 65536 + o] = v;
        idxp[jh * 65536 + o] = j;
    }
}

// ------------------------------------------------- gather + LN(32) + head-sum
__global__ __launch_bounds__(256) void k_hsum(const unsigned short* __restrict__ vbf,
        const float* __restrict__ valp, const int* __restrict__ idxp,
        const float* __restrict__ res, const float* __restrict__ g,
        const float* __restrict__ bb, unsigned short* __restrict__ u) {
    __shared__ float rel[32][8][33];
    int t = threadIdx.x;
    int rowBase = blockIdx.x * 32;
    int rw = t >> 3, h = t & 7;
    int bn = rowBase + rw;
    int b = bn >> 10, i = bn & 1023;
    int o = (b * H_ + h) * N_ + i;
    float v0 = valp[o], v1 = valp[65536 + o];
    int j = (v1 > v0) ? idxp[65536 + o] : idxp[o];
    const uint4* src = (const uint4*)(vbf + (size_t)(b * N_ + j) * 256 + h * 32);
    float v[32];
    #pragma unroll
    for (int c = 0; c < 4; ++c) {
        uint4 uu = src[c];
        v[c*8+0] = bf2f((unsigned short)(uu.x & 0xffff));
        v[c*8+1] = bf2f((unsigned short)(uu.x >> 16));
        v[c*8+2] = bf2f((unsigned short)(uu.y & 0xffff));
        v[c*8+3] = bf2f((unsigned short)(uu.y >> 16));
        v[c*8+4] = bf2f((unsigned short)(uu.z & 0xffff));
        v[c*8+5] = bf2f((unsigned short)(uu.z >> 16));
        v[c*8+6] = bf2f((unsigned short)(uu.w & 0xffff));
        v[c*8+7] = bf2f((unsigned short)(uu.w >> 16));
    }
    float s = 0.f, sq = 0.f;
    #pragma unroll
    for (int d = 0; d < 32; ++d) { s += v[d]; sq += v[d]*v[d]; }
    float m = s * (1.f/32.f), var = sq * (1.f/32.f) - m * m;
    float rs = rsqrtf(var + 1e-5f);
    #pragma unroll
    for (int d = 0; d < 32; ++d)
        rel[rw][h][d] = (v[d] - m) * rs * g[d] + bb[d];
    __syncthreads();
    #pragma unroll
    for (int e = t; e < 1024; e += 256) {
        int r = e >> 5, d = e & 31;
        float acc = 0.f;
        #pragma unroll
        for (int hh = 0; hh < 8; ++hh) acc += rel[r][hh][d];
        u[(rowBase + r) * 64 + d]      = f2bf(acc);
        u[(rowBase + r) * 64 + 32 + d] = f2bf(8.f * res[(rowBase + r) * 32 + d]);
    }
}

// ------------------------------------------------- mid = gelu(u @ w_inner + 8*b_inner)
__global__ __launch_bounds__(256) void k_mid(const unsigned short* __restrict__ u,
        const unsigned short* __restrict__ wiT, const float* __restrict__ b_inner,
        unsigned short* __restrict__ mid) {
    __shared__ __align__(16) unsigned short As[4096];
    __shared__ __align__(16) unsigned short Bs[4096];
    int t = threadIdx.x;
    int rowBase = blockIdx.x * 64, colBase = blockIdx.y * 64;
    int l = t & 63, w = t >> 6, wr = w >> 1, wc = w & 1;
    int r = t >> 2, cA = (t & 3) * 2;
    {
        uint4 a0 = *(const uint4*)(u   + (size_t)(rowBase + r) * 64 + cA * 8);
        uint4 a1 = *(const uint4*)(u   + (size_t)(rowBase + r) * 64 + cA * 8 + 8);
        uint4 b0 = *(const uint4*)(wiT + (size_t)(colBase + r) * 64 + cA * 8);
        uint4 b1 = *(const uint4*)(wiT + (size_t)(colBase + r) * 64 + cA * 8 + 8);
        *(uint4*)&As[(r * 8 + ( cA      ^ (r & 7))) * 8] = a0;
        *(uint4*)&As[(r * 8 + ((cA + 1) ^ (r & 7))) * 8] = a1;
        *(uint4*)&Bs[(r * 8 + ( cA      ^ (r & 7))) * 8] = b0;
        *(uint4*)&Bs[(r * 8 + ((cA + 1) ^ (r & 7))) * 8] = b1;
    }
    __syncthreads();
    f32x4 acc00 = {0.f,0.f,0.f,0.f}, acc01 = acc00, acc10 = acc00, acc11 = acc00;
    int m = l & 15, g = l >> 4;
    int swm = m & 7;
    #pragma unroll
    for (int ks = 0; ks < 2; ++ks) {
        int kc = ks * 4 + g;
        int sc = kc ^ swm;
        s16x8 a0 = *(const s16x8*)&As[((wr*32      + m) * 8 + sc) * 8];
        s16x8 a1 = *(const s16x8*)&As[((wr*32 + 16 + m) * 8 + sc) * 8];
        s16x8 b0 = *(const s16x8*)&Bs[((wc*32      + m) * 8 + sc) * 8];
        s16x8 b1 = *(const s16x8*)&Bs[((wc*32 + 16 + m) * 8 + sc) * 8];
        acc00 = __builtin_amdgcn_mfma_f32_16x16x32_bf16(a0, b0, acc00, 0, 0, 0);
        acc01 = __builtin_amdgcn_mfma_f32_16x16x32_bf16(a0, b1, acc01, 0, 0, 0);
        acc10 = __builtin_amdgcn_mfma_f32_16x16x32_bf16(a1, b0, acc10, 0, 0, 0);
        acc11 = __builtin_amdgcn_mfma_f32_16x16x32_bf16(a1, b1, acc11, 0, 0, 0);
    }
    #pragma unroll
    for (int fr = 0; fr < 2; ++fr) {
        #pragma unroll
        for (int fc = 0; fc < 2; ++fc) {
            f32x4 A = fr == 0 ? (fc == 0 ? acc00 : acc01)
                              : (fc == 0 ? acc10 : acc11);
            int col = colBase + wc * 32 + fc * 16 + m;
            float bi = 8.f * b_inner[col];
            #pragma unroll
            for (int rr = 0; rr < 4; ++rr) {
                int row = rowBase + wr * 32 + fr * 16 + g * 4 + rr;
                mid[(size_t)row * HID_ + col] = f2bf(gelu(A[rr] + bi));
            }
        }
    }
}

// ------------------------------------------------- out = mid @ w_outer + b_outer + x
__global__ __launch_bounds__(256) void k_out(const unsigned short* __restrict__ mid,
        const unsigned short* __restrict__ woT, const float* __restrict__ b_outer,
        const float* __restrict__ x, float* __restrict__ out) {
    __shared__ __align__(16) unsigned short As[2][4096];
    __shared__ __align__(16) unsigned short Bs[2][4096];
    int t = threadIdx.x;
    int rowBase = blockIdx.x * 64, colBase = blockIdx.y * 64;
    int l = t & 63, w = t >> 6, wr = w >> 1, wc = w & 1;
    int r0 = t >> 3,        c0 = t & 7;
    int r1 = (t + 256) >> 3, c1 = t & 7;
    int s0 = (r0 * 8 + (c0 ^ (r0 & 7))) * 8;
    int s1 = (r1 * 8 + (c1 ^ (r1 & 7))) * 8;
    f32x4 acc00 = {0.f,0.f,0.f,0.f}, acc01 = acc00, acc10 = acc00, acc11 = acc00;
    int m = l & 15, g = l >> 4;
    int swm = m & 7;
    {
        uint4 va0 = *(const uint4*)(mid + (size_t)(rowBase + r0) * 1024 + c0 * 8);
        uint4 va1 = *(const uint4*)(mid + (size_t)(rowBase + r1) * 1024 + c1 * 8);
        uint4 vb0 = *(const uint4*)(woT + (size_t)(colBase + r0) * 1024 + c0 * 8);
        uint4 vb1 = *(const uint4*)(woT + (size_t)(colBase + r1) * 1024 + c1 * 8);
        *(uint4*)&As[0][s0] = va0; *(uint4*)&As[0][s1] = va1;
        *(uint4*)&Bs[0][s0] = vb0; *(uint4*)&Bs[0][s1] = vb1;
    }
    __syncthreads();
    int cur = 0;
    for (int kt = 0; kt < 16; ++kt) {
        uint4 va0, va1, vb0, vb1;
        bool pf = (kt + 1) < 16;
        if (pf) {
            int k0 = (kt + 1) * 64;
            va0 = *(const uint4*)(mid + (size_t)(rowBase + r0) * 1024 + k0 + c0 * 8);
            va1 = *(const uint4*)(mid + (size_t)(rowBase + r1) * 1024 + k0 + c1 * 8);
            vb0 = *(const uint4*)(woT + (size_t)(colBase + r0) * 1024 + k0 + c0 * 8);
            vb1 = *(const uint4*)(woT + (size_t)(colBase + r1) * 1024 + k0 + c1 * 8);
        }
        #pragma unroll
        for (int ks = 0; ks < 2; ++ks) {
            int kc = ks * 4 + g;
            int sc = kc ^ swm;
            s16x8 a0 = *(const s16x8*)&As[cur][((wr*32      + m) * 8 + sc) * 8];
            s16x8 a1 = *(const s16x8*)&As[cur][((wr*32 + 16 + m) * 8 + sc) * 8];
            s16x8 b0 = *(const s16x8*)&Bs[cur][((wc*32      + m) * 8 + sc) * 8];
            s16x8 b1 = *(const s16x8*)&Bs[cur][((wc*32 + 16 + m) * 8 + sc) * 8];
            acc00 = __builtin_amdgcn_mfma_f32_16x16x32_bf16(a0, b0, acc00, 0, 0, 0);
            acc01 = __builtin_amdgcn_mfma_f32_16x16x32_bf16(a0, b1, acc01, 0, 0, 0);
            acc10 = __builtin_amdgcn_mfma_f32_16x16x32_bf16(a1, b0, acc10, 0, 0, 0);
            acc11 = __builtin_amdgcn_mfma_f32_16x16x32_bf16(a1, b1, acc11, 0, 0, 0);
        }
        if (pf) {
            *(uint4*)&As[cur ^ 1][s0] = va0; *(uint4*)&As[cur ^ 1][s1] = va1;
            *(uint4*)&Bs[cur ^ 1][s0] = vb0; *(uint4*)&Bs[cur ^ 1][s1] = vb1;
        }
        __syncthreads();
        cur ^= 1;
    }
    #pragma unroll
    for (int fr = 0; fr < 2; ++fr) {
        #pragma unroll
        for (int fc = 0; fc < 2; ++fc) {
            f32x4 A = fr == 0 ? (fc == 0 ? acc00 : acc01)
                              : (fc == 0 ? acc10 : acc11);
            int col = colBase + wc * 32 + fc * 16 + m;
            float bo = b_outer[col];
            #pragma unroll
            for (int rr = 0; rr < 4; ++rr) {
                int row = rowBase + wr * 32 + fr * 16 + g * 4 + rr;
                out[(size_t)row * 256 + col] = A[rr] + bo + x[(size_t)row * 256 + col];
            }
        }
    }
}

extern "C" void kernel_launch(void* const* d_in, const int* in_sizes, int n_in,
                              void* d_out, int out_size, void* d_ws, size_t ws_size,
                              hipStream_t stream) {
    const float* x        = (const float*)d_in[0];
    const float* w_q      = (const float*)d_in[1];
    const float* w_kv     = (const float*)d_in[2];
    const float* ln_out_g = (const float*)d_in[3];
    const float* ln_out_b = (const float*)d_in[4];
    const float* ln_rel_g = (const float*)d_in[5];
    const float* ln_rel_b = (const float*)d_in[6];
    const float* w_down   = (const float*)d_in[7];
    const float* b_down   = (const float*)d_in[8];
    const float* w_inner  = (const float*)d_in[9];
    const float* b_inner  = (const float*)d_in[10];
    const float* w_outer  = (const float*)d_in[11];
    const float* b_outer  = (const float*)d_in[12];
    float* out = (float*)d_out;

    float* ws = (float*)d_ws;
    float* pre = ws;                                          // [0, 2,097,152)
    unsigned short* pbf = (unsigned short*)(ws + 2097152);    // -> 3,145,728
    f16* khi = (f16*)(ws + 3145728);                          // -> 4,194,304
    f16* klo = (f16*)(ws + 4194304);                          // -> 5,242,880
    unsigned short* vbf = (unsigned short*)(ws + 5242880);    // -> 6,291,456
    f16* qhi = (f16*)(ws + 6291456);                          // -> 6,422,528
    f16* qlo = (f16*)(ws + 6422528);                          // -> 6,553,600
    float* resbuf = ws + 6553600;                             // -> 6,815,744
    unsigned short* ubuf = (unsigned short*)(ws + 6815744);   // -> 7,077,888
    float* valp = ws + 7077888;                               // -> 7,208,960
    int* idxp = (int*)(ws + 7208960);                         // -> 7,340,032
    unsigned short* woT = (unsigned short*)(ws + 7340032);    // -> 7,471,104
    unsigned short* wiT = (unsigned short*)(ws + 7471104);    // -> 7,503,872
    unsigned short* wvT = ubuf;            // alias: dead before k_hsum writes ubuf
    unsigned short* mid = (unsigned short*)ws;  // aliases pre/pbf/khi (dead by k_mid)

    k_ln<<<2048, 256, 0, stream>>>(x, ln_out_g, ln_out_b, pre, pbf);
    k_gemmK<<<dim3(5, 128), 256, 0, stream>>>(pre, w_kv, w_q, khi, klo, qhi, qlo);
    k_prep<<<224, 256, 0, stream>>>(x, w_down, b_down, w_kv, w_outer, w_inner,
                                    resbuf, wvT, woT, wiT);
    k_gemmV<<<dim3(128, 4), 256, 0, stream>>>(pbf, wvT, vbf);
    k_argmax<<<2048, 256, 0, stream>>>(qhi, qlo, khi, klo, valp, idxp);
    k_hsum<<<256, 256, 0, stream>>>(vbf, valp, idxp, resbuf, ln_rel_g, ln_rel_b, ubuf);
    k_mid<<<dim3(128, 16), 256, 0, stream>>>(ubuf, wiT, b_inner, mid);
    k_out<<<dim3(128, 4), 256, 0, stream>>>(mid, woT, b_outer, x, out);
}